// Round 3
// baseline (360.388 us; speedup 1.0000x reference)
//
#include <hip/hip_runtime.h>
#include <hip/hip_fp16.h>

typedef _Float16 f16;
typedef _Float16 f16x8 __attribute__((ext_vector_type(8)));
typedef __fp16 h16x2 __attribute__((ext_vector_type(2)));
typedef float f32x4 __attribute__((ext_vector_type(4)));
typedef float f32x16 __attribute__((ext_vector_type(16)));

#define LOG2E 1.4426950408889634f
#define NSL 0.2f

// ---------------- Kernel 1: graph -> transposed bitmask (+ init M2e) ----------------
// maskT[i][jw] bit b = (graph[jw*32+b][i] > 0)
__global__ __launch_bounds__(256) void k_mask(const int* __restrict__ graph,
                                              unsigned int* __restrict__ maskT,
                                              unsigned int* __restrict__ M2e) {
    if (blockIdx.x == 0 && threadIdx.x < 8) M2e[threadIdx.x] = 0x007FFFFFu;  // enc(-inf)
    __shared__ unsigned long long bal[4][64];
    int w = threadIdx.x >> 6;
    int lane = threadIdx.x & 63;
    int gw = blockIdx.x * 4 + w;      // 4096 waves, one 64x64 bit tile each
    int ti = gw & 63, tj = gw >> 6;
    int i0 = ti * 64, j0 = tj * 64;
    #pragma unroll 8
    for (int k = 0; k < 64; k++) {
        int g = graph[(j0 + k) * 4096 + i0 + lane];
        unsigned long long b = __ballot(g > 0);
        if (lane == 0) bal[w][k] = b;
    }
    __syncthreads();
    unsigned long long word = 0;
    #pragma unroll 8
    for (int k = 0; k < 64; k++) {
        word |= ((bal[w][k] >> lane) & 1ull) << k;
    }
    uint2 st; st.x = (unsigned int)word; st.y = (unsigned int)(word >> 32);
    *(uint2*)&maskT[(unsigned)(i0 + lane) * 128u + (unsigned)(j0 >> 5)] = st;
}

// ---------------- Kernel 2: fp32 [R][C] -> f16 [C][R] transpose ----------------
__global__ __launch_bounds__(256) void k_transpose(const float* __restrict__ in,
                                                   f16* __restrict__ out, int R, int C) {
    __shared__ float tile[32][33];
    int tx = threadIdx.x & 31, ty = threadIdx.x >> 5;
    int c0 = blockIdx.x * 32, r0 = blockIdx.y * 32;
    for (int rr = ty; rr < 32; rr += 8)
        tile[rr][tx] = in[(r0 + rr) * C + c0 + tx];
    __syncthreads();
    for (int rr = ty; rr < 32; rr += 8)
        out[(size_t)(c0 + rr) * R + r0 + tx] = (f16)tile[tx][rr];
}

// ---------------- Kernel 2b: x fp32 [4096][512] -> xh2 f16 swizzled [(k>>4)][row][k&15] ----------------
__global__ __launch_bounds__(256) void k_xcvt(const float* __restrict__ x,
                                              f16* __restrict__ xh2) {
    int id = blockIdx.x * 256 + threadIdx.x;   // 131072
    int row = id & 4095, kt = id >> 12;
    const float4* xs = (const float4*)(x + (size_t)row * 512 + kt * 16);
    float4 u0 = xs[0], u1 = xs[1], u2 = xs[2], u3 = xs[3];
    union { int4 a[2]; h16x2 p[8]; } px;
    px.p[0] = __builtin_amdgcn_cvt_pkrtz(u0.x, u0.y);
    px.p[1] = __builtin_amdgcn_cvt_pkrtz(u0.z, u0.w);
    px.p[2] = __builtin_amdgcn_cvt_pkrtz(u1.x, u1.y);
    px.p[3] = __builtin_amdgcn_cvt_pkrtz(u1.z, u1.w);
    px.p[4] = __builtin_amdgcn_cvt_pkrtz(u2.x, u2.y);
    px.p[5] = __builtin_amdgcn_cvt_pkrtz(u2.z, u2.w);
    px.p[6] = __builtin_amdgcn_cvt_pkrtz(u3.x, u3.y);
    px.p[7] = __builtin_amdgcn_cvt_pkrtz(u3.z, u3.w);
    int4* d = (int4*)(xh2 + ((size_t)kt * 4096 + row) * 16);
    d[0] = px.a[0]; d[1] = px.a[1];
}

// ---------------- Kernel 3: hbT2 swizzled [h][(j>>4)*128+f][j&15] = (x @ W[h])^T in f16 ----------------
__global__ __launch_bounds__(256) void k_gemm_h(const f16* __restrict__ xh2,
                                                const f16* __restrict__ Wht,
                                                f16* __restrict__ hbT2) {
    int bx = blockIdx.x;
    int h = bx & 7, jb = bx >> 3;
    int j0 = jb * 64;
    int tid = threadIdx.x;
    int w = tid >> 6, lane = tid & 63;
    int ln = lane & 15, q = lane >> 4;
    f32x4 acc[2][4] = {};
    for (int k0 = 0; k0 < 512; k0 += 32) {
        f16x8 a0 = *(const f16x8*)(Wht + (size_t)(w * 32 + ln) * 4096 + h * 512 + k0 + q * 8);
        f16x8 a1 = *(const f16x8*)(Wht + (size_t)(w * 32 + 16 + ln) * 4096 + h * 512 + k0 + q * 8);
        f16x8 bfr[4];
        #pragma unroll
        for (int nt = 0; nt < 4; nt++) {
            // B[k=m][n=j]: 8 consecutive m at fixed row j from xh2
            int kk = k0 + q * 8;
            bfr[nt] = *(const f16x8*)(xh2 + ((size_t)(kk >> 4) * 4096 + j0 + nt * 16 + ln) * 16
                                      + (kk & 15));
        }
        #pragma unroll
        for (int nt = 0; nt < 4; nt++) {
            acc[0][nt] = __builtin_amdgcn_mfma_f32_16x16x32_f16(a0, bfr[nt], acc[0][nt], 0, 0, 0);
            acc[1][nt] = __builtin_amdgcn_mfma_f32_16x16x32_f16(a1, bfr[nt], acc[1][nt], 0, 0, 0);
        }
    }
    #pragma unroll
    for (int mt = 0; mt < 2; mt++)
        #pragma unroll
        for (int nt = 0; nt < 4; nt++) {
            #pragma unroll
            for (int r = 0; r < 4; r++) {
                int f = w * 32 + mt * 16 + q * 4 + r;
                // j = j0 + nt*16 + ln  ->  tile (j0>>4)+nt, inner ln
                hbT2[(size_t)h * 524288 + (size_t)((j0 >> 4) + nt) * 2048 + f * 16 + ln] =
                    (f16)acc[mt][nt][r];
            }
        }
}

// ---------------- Kernel 4: a2/b2 + per-head atomic max of b2 (encoded) ----------------
__global__ __launch_bounds__(256) void k_ab(const f16* __restrict__ hbT2,
                                            const float* __restrict__ wi,
                                            const float* __restrict__ wj,
                                            float* __restrict__ a2, float* __restrict__ b2,
                                            unsigned int* __restrict__ M2e) {
    __shared__ float swi[128], swj[128], red[256];
    int b = blockIdx.x;           // 128 blocks = 8 heads x 16 chunks
    int h = b & 7, jc = b >> 3;
    int tid = threadIdx.x;
    if (tid < 128) { swi[tid] = wi[h * 128 + tid]; swj[tid] = wj[h * 128 + tid]; }
    __syncthreads();
    int j = jc * 256 + tid;
    float pa = 0.f, pb = 0.f;
    #pragma unroll 8
    for (int f = 0; f < 128; f++) {
        float v = (float)hbT2[(size_t)h * 524288 + (size_t)((j >> 4) * 128 + f) * 16 + (j & 15)];
        pa += v * swi[f];
        pb += v * swj[f];
    }
    a2[h * 4096 + j] = pa * LOG2E;
    float bb = pb * LOG2E;
    b2[h * 4096 + j] = bb;
    red[tid] = bb;
    __syncthreads();
    for (int s = 128; s > 0; s >>= 1) {
        if (tid < s) red[tid] = fmaxf(red[tid], red[tid + s]);
        __syncthreads();
    }
    if (tid == 0) {
        unsigned u = __float_as_uint(red[0]);
        unsigned enc = (u & 0x80000000u) ? ~u : (u | 0x80000000u);
        atomicMax(&M2e[h], enc);
    }
}

// ---------------- Kernel 5: exp tables (fully parallel) ----------------
__global__ __launch_bounds__(256) void k_prep(const float* __restrict__ a2,
                                              const float* __restrict__ b2,
                                              const unsigned int* __restrict__ M2e,
                                              float* __restrict__ ABpre,
                                              float* __restrict__ Bpre) {
    int id = blockIdx.x * 256 + threadIdx.x;   // 32768
    int h = id >> 12;
    unsigned enc = M2e[h];
    unsigned u = (enc & 0x80000000u) ? (enc & 0x7FFFFFFFu) : ~enc;
    float M2 = __uint_as_float(u);
    float av = a2[id];
    float t = av + M2;
    float m2 = fmaxf(t, NSL * t);
    ((float2*)ABpre)[id] = make_float2(exp2f(av - m2), exp2f(NSL * av - m2));
    float bv = b2[id];
    ((float2*)Bpre)[id] = make_float2(exp2f(bv), exp2f(NSL * bv));
}

// ---------------- Kernel 6: main fused masked-softmax GEMM + residual + bias ----------------
// Block: (head h = bx&7 -> XCD-pinned, 32-row i-strip). 4 waves = 4 j-quarters (S=4 split).
// B-fragments read directly from L2-resident swizzled hbT2 -> ZERO barriers in j-loop.
__global__ __launch_bounds__(256, 3) void k_main(const f16* __restrict__ xh2,
                                                 const f16* __restrict__ hbT2,
                                                 const f16* __restrict__ Wrt,
                                                 const unsigned int* __restrict__ maskT,
                                                 const float* __restrict__ ABpre,
                                                 const float* __restrict__ Bpre,
                                                 const float* __restrict__ bias,
                                                 float* __restrict__ out) {
    __shared__ float lds[8192];   // 32 KB: denom exchange then acc exchange

    int bx = blockIdx.x;
    int h = bx & 7, it = bx >> 3;
    int i0 = it * 32;
    int tid = threadIdx.x;
    int w = tid >> 6, lane = tid & 63;
    int nl = lane & 31, half = lane >> 5;
    int i = i0 + nl;

    float2 Av = *(const float2*)(ABpre + 2 * (h * 4096 + i));
    float Ai = Av.x, Ai2 = Av.y;

    const f16x8 onev = {(_Float16)1, (_Float16)1, (_Float16)1, (_Float16)1,
                        (_Float16)1, (_Float16)1, (_Float16)1, (_Float16)1};

    f32x16 acc0 = {}, acc1 = {}, acc2 = {}, acc3 = {}, accs = {};

    const f16* bbase = hbT2 + (size_t)h * 524288 + half * 8;
    const float* bpre = Bpre + 2 * (h * 4096) + half * 16;
    const unsigned int* mrow = maskT + (unsigned)i * 128u;

    for (int jb = 0; jb < 32; jb++) {
        int j0 = w * 1024 + jb * 32;
        unsigned mw = mrow[j0 >> 5];
        #pragma unroll
        for (int t = 0; t < 2; t++) {
            int jt = j0 + t * 16;
            const float4* bp = (const float4*)(bpre + 2 * jt);
            float4 b0 = bp[0], b1 = bp[1], b2v = bp[2], b3 = bp[3];
            int bb = t * 16 + half * 8;

            union { f16x8 v; h16x2 p[4]; } af;
            float v0, v1;
            v0 = fmaxf(Ai * b0.x, Ai2 * b0.y); v1 = fmaxf(Ai * b0.z, Ai2 * b0.w);
            v0 = ((mw >> (bb + 0)) & 1u) ? v0 : 0.f;
            v1 = ((mw >> (bb + 1)) & 1u) ? v1 : 0.f;
            af.p[0] = __builtin_amdgcn_cvt_pkrtz(v0, v1);
            v0 = fmaxf(Ai * b1.x, Ai2 * b1.y); v1 = fmaxf(Ai * b1.z, Ai2 * b1.w);
            v0 = ((mw >> (bb + 2)) & 1u) ? v0 : 0.f;
            v1 = ((mw >> (bb + 3)) & 1u) ? v1 : 0.f;
            af.p[1] = __builtin_amdgcn_cvt_pkrtz(v0, v1);
            v0 = fmaxf(Ai * b2v.x, Ai2 * b2v.y); v1 = fmaxf(Ai * b2v.z, Ai2 * b2v.w);
            v0 = ((mw >> (bb + 4)) & 1u) ? v0 : 0.f;
            v1 = ((mw >> (bb + 5)) & 1u) ? v1 : 0.f;
            af.p[2] = __builtin_amdgcn_cvt_pkrtz(v0, v1);
            v0 = fmaxf(Ai * b3.x, Ai2 * b3.y); v1 = fmaxf(Ai * b3.z, Ai2 * b3.w);
            v0 = ((mw >> (bb + 6)) & 1u) ? v0 : 0.f;
            v1 = ((mw >> (bb + 7)) & 1u) ? v1 : 0.f;
            af.p[3] = __builtin_amdgcn_cvt_pkrtz(v0, v1);

            const f16* bt = bbase + (size_t)(jt >> 4) * 2048;
            f16x8 bf0 = *(const f16x8*)(bt + (0 * 32 + nl) * 16);
            f16x8 bf1 = *(const f16x8*)(bt + (1 * 32 + nl) * 16);
            f16x8 bf2 = *(const f16x8*)(bt + (2 * 32 + nl) * 16);
            f16x8 bf3 = *(const f16x8*)(bt + (3 * 32 + nl) * 16);

            acc0 = __builtin_amdgcn_mfma_f32_32x32x16_f16(af.v, bf0, acc0, 0, 0, 0);
            acc1 = __builtin_amdgcn_mfma_f32_32x32x16_f16(af.v, bf1, acc1, 0, 0, 0);
            acc2 = __builtin_amdgcn_mfma_f32_32x32x16_f16(af.v, bf2, acc2, 0, 0, 0);
            acc3 = __builtin_amdgcn_mfma_f32_32x32x16_f16(af.v, bf3, acc3, 0, 0, 0);
            accs = __builtin_amdgcn_mfma_f32_32x32x16_f16(af.v, onev, accs, 0, 0, 0);
        }
    }

    // ---- cross-wave denominator reduction (rows follow C/D layout: (r&3)+8*(r>>2)+4*half) ----
    {
        float* sp = lds + w * 1088 + lane * 17;
        #pragma unroll
        for (int r = 0; r < 16; r++) sp[r] = accs[r];
    }
    __syncthreads();
    #pragma unroll
    for (int r = 0; r < 16; r++) {
        float s = lds[0 * 1088 + lane * 17 + r] + lds[1 * 1088 + lane * 17 + r]
                + lds[2 * 1088 + lane * 17 + r] + lds[3 * 1088 + lane * 17 + r];
        float rv = 1.0f / s;
        acc0[r] *= rv; acc1[r] *= rv; acc2[r] *= rv; acc3[r] *= rv;
    }

    // ---- residual: acc += x @ Wr[:, h-slice], k-quarter per wave ----
    {
        const f16* wt = Wrt + (size_t)(h * 128) * 512 + half * 8;
        int k0b = w * 128;
        #pragma unroll
        for (int kk = 0; kk < 8; kk++) {
            int k0 = k0b + kk * 16;
            f16x8 ax = *(const f16x8*)(xh2 + ((size_t)(k0 >> 4) * 4096 + i) * 16 + half * 8);
            f16x8 w0 = *(const f16x8*)(wt + (size_t)(0 * 32 + nl) * 512 + k0);
            f16x8 w1 = *(const f16x8*)(wt + (size_t)(1 * 32 + nl) * 512 + k0);
            f16x8 w2 = *(const f16x8*)(wt + (size_t)(2 * 32 + nl) * 512 + k0);
            f16x8 w3 = *(const f16x8*)(wt + (size_t)(3 * 32 + nl) * 512 + k0);
            acc0 = __builtin_amdgcn_mfma_f32_32x32x16_f16(ax, w0, acc0, 0, 0, 0);
            acc1 = __builtin_amdgcn_mfma_f32_32x32x16_f16(ax, w1, acc1, 0, 0, 0);
            acc2 = __builtin_amdgcn_mfma_f32_32x32x16_f16(ax, w2, acc2, 0, 0, 0);
            acc3 = __builtin_amdgcn_mfma_f32_32x32x16_f16(ax, w3, acc3, 0, 0, 0);
        }
    }

    // ---- cross-wave accumulator reduction (XOR-swizzled b128, conflict-free) ----
    __syncthreads();   // denom reads done; lds reusable
    union uu { f32x16 v; f32x4 q[4]; };
    int sw = (lane & 7) << 2;
    if (w >= 2) {
        float* dp = lds + (w - 2) * 4096 + lane * 64;
        uu u0; u0.v = acc0; uu u1; u1.v = acc1; uu u2; u2.v = acc2; uu u3; u3.v = acc3;
        #pragma unroll
        for (int q4 = 0; q4 < 4; q4++) {
            *(f32x4*)(dp + ((0 + q4 * 4) ^ sw))  = u0.q[q4];
            *(f32x4*)(dp + ((16 + q4 * 4) ^ sw)) = u1.q[q4];
            *(f32x4*)(dp + ((32 + q4 * 4) ^ sw)) = u2.q[q4];
            *(f32x4*)(dp + ((48 + q4 * 4) ^ sw)) = u3.q[q4];
        }
    }
    __syncthreads();
    if (w < 2) {
        const float* dp = lds + w * 4096 + lane * 64;
        uu u0; u0.v = acc0; uu u1; u1.v = acc1; uu u2; u2.v = acc2; uu u3; u3.v = acc3;
        #pragma unroll
        for (int q4 = 0; q4 < 4; q4++) {
            u0.q[q4] += *(const f32x4*)(dp + ((0 + q4 * 4) ^ sw));
            u1.q[q4] += *(const f32x4*)(dp + ((16 + q4 * 4) ^ sw));
            u2.q[q4] += *(const f32x4*)(dp + ((32 + q4 * 4) ^ sw));
            u3.q[q4] += *(const f32x4*)(dp + ((48 + q4 * 4) ^ sw));
        }
        acc0 = u0.v; acc1 = u1.v; acc2 = u2.v; acc3 = u3.v;
    }
    __syncthreads();
    if (w == 1) {
        float* dp = lds + lane * 64;
        uu u0; u0.v = acc0; uu u1; u1.v = acc1; uu u2; u2.v = acc2; uu u3; u3.v = acc3;
        #pragma unroll
        for (int q4 = 0; q4 < 4; q4++) {
            *(f32x4*)(dp + ((0 + q4 * 4) ^ sw))  = u0.q[q4];
            *(f32x4*)(dp + ((16 + q4 * 4) ^ sw)) = u1.q[q4];
            *(f32x4*)(dp + ((32 + q4 * 4) ^ sw)) = u2.q[q4];
            *(f32x4*)(dp + ((48 + q4 * 4) ^ sw)) = u3.q[q4];
        }
    }
    __syncthreads();
    if (w == 0) {
        const float* dp = lds + lane * 64;
        uu u0; u0.v = acc0; uu u1; u1.v = acc1; uu u2; u2.v = acc2; uu u3; u3.v = acc3;
        #pragma unroll
        for (int q4 = 0; q4 < 4; q4++) {
            u0.q[q4] += *(const f32x4*)(dp + ((0 + q4 * 4) ^ sw));
            u1.q[q4] += *(const f32x4*)(dp + ((16 + q4 * 4) ^ sw));
            u2.q[q4] += *(const f32x4*)(dp + ((32 + q4 * 4) ^ sw));
            u3.q[q4] += *(const f32x4*)(dp + ((48 + q4 * 4) ^ sw));
        }
        // ---- epilogue: + bias, store ----
        float bv0 = bias[h * 128 + 0 * 32 + nl];
        float bv1 = bias[h * 128 + 1 * 32 + nl];
        float bv2 = bias[h * 128 + 2 * 32 + nl];
        float bv3 = bias[h * 128 + 3 * 32 + nl];
        #pragma unroll
        for (int r = 0; r < 16; r++) {
            int row = i0 + (r & 3) + 8 * (r >> 2) + 4 * half;
            float* op = out + (size_t)row * 1024 + h * 128 + nl;
            op[0]  = u0.v[r] + bv0;
            op[32] = u1.v[r] + bv1;
            op[64] = u2.v[r] + bv2;
            op[96] = u3.v[r] + bv3;
        }
    }
}

extern "C" void kernel_launch(void* const* d_in, const int* in_sizes, int n_in,
                              void* d_out, int out_size, void* d_ws, size_t ws_size,
                              hipStream_t stream) {
    (void)in_sizes; (void)n_in; (void)out_size; (void)ws_size;
    const float* x     = (const float*)d_in[0];
    const int*   graph = (const int*)d_in[1];
    const float* W     = (const float*)d_in[2];
    const float* wi    = (const float*)d_in[3];
    const float* wj    = (const float*)d_in[4];
    const float* Wr    = (const float*)d_in[5];
    const float* bias  = (const float*)d_in[6];
    float* out = (float*)d_out;

    char* ws = (char*)d_ws;
    unsigned int* maskT = (unsigned int*)ws;              // 2 MB  [4096][128] bits
    f16* hbT2  = (f16*)(ws + (2u << 20));                 // 8 MB  [8][256*128][16] swizzled
    f16* Wht   = (f16*)(ws + (10u << 20));                // 1 MB  [128][4096]  (W^T)
    f16* Wrt   = (f16*)(ws + (11u << 20));                // 1 MB  [1024][512]  (W_r^T)
    f16* xh2   = (f16*)(ws + (12u << 20));                // 4 MB  [32][4096][16] swizzled
    float* a2    = (float*)(ws + (16u << 20));            // 128 KB
    float* b2    = a2 + 8 * 4096;                         // 128 KB
    float* ABpre = b2 + 8 * 4096;                         // 256 KB (float2)
    float* Bpre  = ABpre + 2 * 8 * 4096;                  // 256 KB (float2)
    unsigned int* M2e = (unsigned int*)(Bpre + 2 * 8 * 4096);  // 32 B

    hipLaunchKernelGGL(k_mask, dim3(1024), dim3(256), 0, stream, graph, maskT, M2e);
    hipLaunchKernelGGL(k_transpose, dim3(4, 128), dim3(256), 0, stream, W, Wht, 4096, 128);
    hipLaunchKernelGGL(k_transpose, dim3(32, 16), dim3(256), 0, stream, Wr, Wrt, 512, 1024);
    hipLaunchKernelGGL(k_xcvt, dim3(512), dim3(256), 0, stream, x, xh2);
    hipLaunchKernelGGL(k_gemm_h, dim3(512), dim3(256), 0, stream, xh2, Wht, hbT2);
    hipLaunchKernelGGL(k_ab, dim3(128), dim3(256), 0, stream, hbT2, wi, wj, a2, b2, M2e);
    hipLaunchKernelGGL(k_prep, dim3(128), dim3(256), 0, stream, a2, b2, M2e, ABpre, Bpre);
    hipLaunchKernelGGL(k_main, dim3(1024), dim3(256), 0, stream, xh2, hbT2, Wrt, maskT,
                       ABpre, Bpre, bias, out);
}

// Round 4
// 298.990 us; speedup vs baseline: 1.2054x; 1.2054x over previous
//
#include <hip/hip_runtime.h>
#include <hip/hip_fp16.h>

typedef _Float16 f16;
typedef _Float16 f16x8 __attribute__((ext_vector_type(8)));
typedef __fp16 h16x2 __attribute__((ext_vector_type(2)));
typedef float f32x4 __attribute__((ext_vector_type(4)));

#define LOG2E 1.4426950408889634f
#define NSL 0.2f

// ---------------- Kernel 1: graph -> transposed bitmask (+ init M2e) ----------------
__global__ __launch_bounds__(256) void k_mask(const int* __restrict__ graph,
                                              unsigned int* __restrict__ maskT,
                                              unsigned int* __restrict__ M2e) {
    if (blockIdx.x == 0 && threadIdx.x < 8) M2e[threadIdx.x] = 0x007FFFFFu;  // enc(-inf)
    __shared__ unsigned long long bal[4][64];
    int w = threadIdx.x >> 6;
    int lane = threadIdx.x & 63;
    int gw = blockIdx.x * 4 + w;
    int ti = gw & 63, tj = gw >> 6;
    int i0 = ti * 64, j0 = tj * 64;
    #pragma unroll 8
    for (int k = 0; k < 64; k++) {
        int g = graph[(j0 + k) * 4096 + i0 + lane];
        unsigned long long b = __ballot(g > 0);
        if (lane == 0) bal[w][k] = b;
    }
    __syncthreads();
    unsigned long long word = 0;
    #pragma unroll 8
    for (int k = 0; k < 64; k++) {
        word |= ((bal[w][k] >> lane) & 1ull) << k;
    }
    uint2 st; st.x = (unsigned int)word; st.y = (unsigned int)(word >> 32);
    *(uint2*)&maskT[(unsigned)(i0 + lane) * 128u + (unsigned)(j0 >> 5)] = st;
}

// ---------------- Kernel 2 (fused prep): xcvt + W transpose + Wr transpose ----------------
__device__ void dev_transpose(const float* __restrict__ in, f16* __restrict__ out,
                              int R, int C, int bxx, int byy, int tid) {
    __shared__ float tile[32][33];
    int tx = tid & 31, ty = tid >> 5;
    int c0 = bxx * 32, r0 = byy * 32;
    for (int rr = ty; rr < 32; rr += 8)
        tile[rr][tx] = in[(r0 + rr) * C + c0 + tx];
    __syncthreads();
    for (int rr = ty; rr < 32; rr += 8)
        out[(size_t)(c0 + rr) * R + r0 + tx] = (f16)tile[tx][rr];
}

__global__ __launch_bounds__(256) void k_pre(const float* __restrict__ x,
                                             f16* __restrict__ xh2,
                                             const float* __restrict__ W,
                                             f16* __restrict__ Wht,
                                             const float* __restrict__ Wr,
                                             f16* __restrict__ Wrt) {
    int bx = blockIdx.x;
    int tid = threadIdx.x;
    if (bx < 512) {
        int id = bx * 256 + tid;   // 131072
        int row = id & 4095, kt = id >> 12;
        const float4* xs = (const float4*)(x + (size_t)row * 512 + kt * 16);
        float4 u0 = xs[0], u1 = xs[1], u2 = xs[2], u3 = xs[3];
        union { int4 a[2]; h16x2 p[8]; } px;
        px.p[0] = __builtin_amdgcn_cvt_pkrtz(u0.x, u0.y);
        px.p[1] = __builtin_amdgcn_cvt_pkrtz(u0.z, u0.w);
        px.p[2] = __builtin_amdgcn_cvt_pkrtz(u1.x, u1.y);
        px.p[3] = __builtin_amdgcn_cvt_pkrtz(u1.z, u1.w);
        px.p[4] = __builtin_amdgcn_cvt_pkrtz(u2.x, u2.y);
        px.p[5] = __builtin_amdgcn_cvt_pkrtz(u2.z, u2.w);
        px.p[6] = __builtin_amdgcn_cvt_pkrtz(u3.x, u3.y);
        px.p[7] = __builtin_amdgcn_cvt_pkrtz(u3.z, u3.w);
        int4* d = (int4*)(xh2 + ((size_t)kt * 4096 + row) * 16);
        d[0] = px.a[0]; d[1] = px.a[1];
    } else if (bx < 1024) {
        int id = bx - 512;                       // W: [4096][128] -> Wht [128][4096]
        dev_transpose(W, Wht, 4096, 128, id & 3, id >> 2, tid);
    } else {
        int id = bx - 1024;                      // Wr: [512][1024] -> Wrt [1024][512]
        dev_transpose(Wr, Wrt, 512, 1024, id & 31, id >> 5, tid);
    }
}

// ---------------- Kernel 3: hbT2 swizzled [h][(j>>4)*128+f][j&15] ----------------
__global__ __launch_bounds__(256) void k_gemm_h(const f16* __restrict__ xh2,
                                                const f16* __restrict__ Wht,
                                                f16* __restrict__ hbT2) {
    int bx = blockIdx.x;
    int h = bx & 7, jb = bx >> 3;
    int j0 = jb * 64;
    int tid = threadIdx.x;
    int w = tid >> 6, lane = tid & 63;
    int ln = lane & 15, q = lane >> 4;
    f32x4 acc[2][4] = {};
    for (int k0 = 0; k0 < 512; k0 += 32) {
        f16x8 a0 = *(const f16x8*)(Wht + (size_t)(w * 32 + ln) * 4096 + h * 512 + k0 + q * 8);
        f16x8 a1 = *(const f16x8*)(Wht + (size_t)(w * 32 + 16 + ln) * 4096 + h * 512 + k0 + q * 8);
        f16x8 bfr[4];
        #pragma unroll
        for (int nt = 0; nt < 4; nt++) {
            int kk = k0 + q * 8;
            bfr[nt] = *(const f16x8*)(xh2 + ((size_t)(kk >> 4) * 4096 + j0 + nt * 16 + ln) * 16
                                      + (kk & 15));
        }
        #pragma unroll
        for (int nt = 0; nt < 4; nt++) {
            acc[0][nt] = __builtin_amdgcn_mfma_f32_16x16x32_f16(a0, bfr[nt], acc[0][nt], 0, 0, 0);
            acc[1][nt] = __builtin_amdgcn_mfma_f32_16x16x32_f16(a1, bfr[nt], acc[1][nt], 0, 0, 0);
        }
    }
    #pragma unroll
    for (int mt = 0; mt < 2; mt++)
        #pragma unroll
        for (int nt = 0; nt < 4; nt++) {
            #pragma unroll
            for (int r = 0; r < 4; r++) {
                int f = w * 32 + mt * 16 + q * 4 + r;
                hbT2[(size_t)h * 524288 + (size_t)((j0 >> 4) + nt) * 2048 + f * 16 + ln] =
                    (f16)acc[mt][nt][r];
            }
        }
}

// ---------------- Kernel 4: a2/b2 + per-head atomic max of b2 (encoded) ----------------
__global__ __launch_bounds__(256) void k_ab(const f16* __restrict__ hbT2,
                                            const float* __restrict__ wi,
                                            const float* __restrict__ wj,
                                            float* __restrict__ a2, float* __restrict__ b2,
                                            unsigned int* __restrict__ M2e) {
    __shared__ float swi[128], swj[128], red[256];
    int b = blockIdx.x;
    int h = b & 7, jc = b >> 3;
    int tid = threadIdx.x;
    if (tid < 128) { swi[tid] = wi[h * 128 + tid]; swj[tid] = wj[h * 128 + tid]; }
    __syncthreads();
    int j = jc * 256 + tid;
    float pa = 0.f, pb = 0.f;
    #pragma unroll 8
    for (int f = 0; f < 128; f++) {
        float v = (float)hbT2[(size_t)h * 524288 + (size_t)((j >> 4) * 128 + f) * 16 + (j & 15)];
        pa += v * swi[f];
        pb += v * swj[f];
    }
    a2[h * 4096 + j] = pa * LOG2E;
    float bb = pb * LOG2E;
    b2[h * 4096 + j] = bb;
    red[tid] = bb;
    __syncthreads();
    for (int s = 128; s > 0; s >>= 1) {
        if (tid < s) red[tid] = fmaxf(red[tid], red[tid + s]);
        __syncthreads();
    }
    if (tid == 0) {
        unsigned u = __float_as_uint(red[0]);
        unsigned enc = (u & 0x80000000u) ? ~u : (u | 0x80000000u);
        atomicMax(&M2e[h], enc);
    }
}

// ---------------- Kernel 5: exp tables ----------------
__global__ __launch_bounds__(256) void k_prep(const float* __restrict__ a2,
                                              const float* __restrict__ b2,
                                              const unsigned int* __restrict__ M2e,
                                              float* __restrict__ ABpre,
                                              float* __restrict__ Bpre) {
    int id = blockIdx.x * 256 + threadIdx.x;   // 32768
    int h = id >> 12;
    unsigned enc = M2e[h];
    unsigned u = (enc & 0x80000000u) ? (enc & 0x7FFFFFFFu) : ~enc;
    float M2 = __uint_as_float(u);
    float av = a2[id];
    float t = av + M2;
    float m2 = fmaxf(t, NSL * t);
    ((float2*)ABpre)[id] = make_float2(exp2f(av - m2), exp2f(NSL * av - m2));
    float bv = b2[id];
    ((float2*)Bpre)[id] = make_float2(exp2f(bv), exp2f(NSL * bv));
}

// ---------------- Kernel 6: main fused masked-softmax GEMM + residual + bias ----------------
// Block = (head h=bx&7, 32-row i-strip). Waves: w&1 = 16-row i-sub, w>>1 = 2048-j half.
// LDS: stage[half][dbuf][128f][40] = 40 KB -> 4 blocks/CU = 16 waves/CU.
__global__ __launch_bounds__(256, 4) void k_main(const f16* __restrict__ xh2,
                                                 const f16* __restrict__ hbT2,
                                                 const f16* __restrict__ Wrt,
                                                 const unsigned int* __restrict__ maskT,
                                                 const float* __restrict__ ABpre,
                                                 const float* __restrict__ Bpre,
                                                 const float* __restrict__ bias,
                                                 float* __restrict__ out) {
    __shared__ f16 stage[2][2][128 * 40];   // 40960 B

    int bx = blockIdx.x;
    int h = bx & 7, it = bx >> 3;
    int i0 = it * 32;
    int tid = threadIdx.x;
    int w = tid >> 6, lane = tid & 63;
    int ln = lane & 15, q = lane >> 4;
    int isub = w & 1, jh = w >> 1;
    int iA = i0 + isub * 16 + ln;

    float2 Av = *(const float2*)(ABpre + 2 * (h * 4096 + iA));
    float Ai = Av.x, Ai2 = Av.y;

    const f16x8 onev = {(_Float16)1, (_Float16)1, (_Float16)1, (_Float16)1,
                        (_Float16)1, (_Float16)1, (_Float16)1, (_Float16)1};

    f32x4 acc[8] = {};
    f32x4 accs = {};

    // staging: 128 threads per half (waves 2jh, 2jh+1), thread-pair-id pid = f row
    int pid = isub * 64 + lane;       // 0..127 within the half's wave pair
    const f16* hsrc = hbT2 + (size_t)h * 524288 + (size_t)(jh * 128) * 2048 + pid * 16;
    f16* hdst0 = &stage[jh][0][0] + pid * 40;
    f16* hdst1 = &stage[jh][1][0] + pid * 40;

    // prologue: stage j-tile 0 of this half
    {
        const int4* s = (const int4*)hsrc;
        int4 v0 = s[0], v1 = s[1];                      // j 0..15
        const int4* s2 = (const int4*)(hsrc + 2048);    // next 16-j tile
        int4 v2 = s2[0], v3 = s2[1];
        int4* d = (int4*)hdst0;
        d[0] = v0; d[1] = v1; d[2] = v2; d[3] = v3;
    }
    __syncthreads();

    const float* bpre = Bpre + 2 * (h * 4096 + jh * 2048);
    const unsigned int* mrow = maskT + (unsigned)iA * 128u + jh * 64;

    int buf = 0;
    for (int kb = 0; kb < 64; kb++) {
        int j0 = kb * 32;
        unsigned mw = mrow[kb];
        const float4* bp = (const float4*)(bpre + 2 * (j0 + q * 8));
        float4 bq0 = bp[0], bq1 = bp[1], bq2 = bp[2], bq3 = bp[3];

        if (kb < 63) {   // prefetch next 32-j tile of this half
            const f16* s = hsrc + (size_t)(kb * 2 + 2) * 2048;
            int4 v0 = ((const int4*)s)[0], v1 = ((const int4*)s)[1];
            int4 v2 = ((const int4*)(s + 2048))[0], v3 = ((const int4*)(s + 2048))[1];
            int4* d = (int4*)(buf ? hdst0 : hdst1);
            d[0] = v0; d[1] = v1; d[2] = v2; d[3] = v3;
        }

        union { f16x8 v; h16x2 p[4]; } af;
        float v0, v1;
        v0 = fmaxf(Ai * bq0.x, Ai2 * bq0.y); v1 = fmaxf(Ai * bq0.z, Ai2 * bq0.w);
        v0 = ((mw >> (q * 8 + 0)) & 1u) ? v0 : 0.f;
        v1 = ((mw >> (q * 8 + 1)) & 1u) ? v1 : 0.f;
        af.p[0] = __builtin_amdgcn_cvt_pkrtz(v0, v1);
        v0 = fmaxf(Ai * bq1.x, Ai2 * bq1.y); v1 = fmaxf(Ai * bq1.z, Ai2 * bq1.w);
        v0 = ((mw >> (q * 8 + 2)) & 1u) ? v0 : 0.f;
        v1 = ((mw >> (q * 8 + 3)) & 1u) ? v1 : 0.f;
        af.p[1] = __builtin_amdgcn_cvt_pkrtz(v0, v1);
        v0 = fmaxf(Ai * bq2.x, Ai2 * bq2.y); v1 = fmaxf(Ai * bq2.z, Ai2 * bq2.w);
        v0 = ((mw >> (q * 8 + 4)) & 1u) ? v0 : 0.f;
        v1 = ((mw >> (q * 8 + 5)) & 1u) ? v1 : 0.f;
        af.p[2] = __builtin_amdgcn_cvt_pkrtz(v0, v1);
        v0 = fmaxf(Ai * bq3.x, Ai2 * bq3.y); v1 = fmaxf(Ai * bq3.z, Ai2 * bq3.w);
        v0 = ((mw >> (q * 8 + 6)) & 1u) ? v0 : 0.f;
        v1 = ((mw >> (q * 8 + 7)) & 1u) ? v1 : 0.f;
        af.p[3] = __builtin_amdgcn_cvt_pkrtz(v0, v1);

        const f16* hb = &stage[jh][buf][0];
        #pragma unroll
        for (int nt = 0; nt < 8; nt++) {
            f16x8 bf = *(const f16x8*)(hb + (nt * 16 + ln) * 40 + q * 8);
            acc[nt] = __builtin_amdgcn_mfma_f32_16x16x32_f16(af.v, bf, acc[nt], 0, 0, 0);
        }
        accs = __builtin_amdgcn_mfma_f32_16x16x32_f16(af.v, onev, accs, 0, 0, 0);

        __syncthreads();
        buf ^= 1;
    }

    // ---- denominator exchange across j-halves (partner wave = w ^ 2) ----
    float* fred = (float*)&stage[0][0][0];
    __syncthreads();
    {
        float* sp = fred + w * 260 + lane * 4;
        sp[0] = accs[0]; sp[1] = accs[1]; sp[2] = accs[2]; sp[3] = accs[3];
    }
    __syncthreads();
    {
        const float* pp = fred + (w ^ 2) * 260 + lane * 4;
        #pragma unroll
        for (int r = 0; r < 4; r++) {
            float rv = 1.0f / (accs[r] + pp[r]);
            #pragma unroll
            for (int nt = 0; nt < 8; nt++) acc[nt][r] *= rv;
        }
    }

    // ---- residual: acc += x @ Wr[:, h-slice]; k-half per j-half (jh) ----
    {
        int k0b = jh * 256;
        #pragma unroll
        for (int kk = 0; kk < 8; kk++) {
            int k0 = k0b + kk * 32;
            f16x8 ax = *(const f16x8*)(xh2 + ((size_t)((k0 >> 4) + (q >> 1)) * 4096 + iA) * 16
                                       + (q & 1) * 8);
            #pragma unroll
            for (int nt = 0; nt < 8; nt++) {
                f16x8 bw = *(const f16x8*)(Wrt + (size_t)(h * 128 + nt * 16 + ln) * 512
                                           + k0 + q * 8);
                acc[nt] = __builtin_amdgcn_mfma_f32_16x16x32_f16(ax, bw, acc[nt], 0, 0, 0);
            }
        }
    }

    // ---- O exchange: waves 2,3 hand partials to waves 0,1; they store ----
    __syncthreads();   // denom reads done, LDS reusable
    if (w >= 2) {
        float* dp = fred + (w - 2) * 2112 + lane * 33;
        #pragma unroll
        for (int nt = 0; nt < 8; nt++)
            *(f32x4*)(dp + nt * 4) = acc[nt];
    }
    __syncthreads();
    if (w < 2) {
        const float* dp = fred + w * 2112 + lane * 33;
        #pragma unroll
        for (int nt = 0; nt < 8; nt++) {
            f32x4 p = *(const f32x4*)(dp + nt * 4);
            int col = h * 128 + nt * 16 + ln;
            float bv = bias[col];
            #pragma unroll
            for (int r = 0; r < 4; r++) {
                int row = i0 + isub * 16 + q * 4 + r;
                out[(size_t)row * 1024 + col] = acc[nt][r] + p[r] + bv;
            }
        }
    }
}

extern "C" void kernel_launch(void* const* d_in, const int* in_sizes, int n_in,
                              void* d_out, int out_size, void* d_ws, size_t ws_size,
                              hipStream_t stream) {
    (void)in_sizes; (void)n_in; (void)out_size; (void)ws_size;
    const float* x     = (const float*)d_in[0];
    const int*   graph = (const int*)d_in[1];
    const float* W     = (const float*)d_in[2];
    const float* wi    = (const float*)d_in[3];
    const float* wj    = (const float*)d_in[4];
    const float* Wr    = (const float*)d_in[5];
    const float* bias  = (const float*)d_in[6];
    float* out = (float*)d_out;

    char* ws = (char*)d_ws;
    unsigned int* maskT = (unsigned int*)ws;              // 2 MB
    f16* hbT2  = (f16*)(ws + (2u << 20));                 // 8 MB  [8][256*128][16] swizzled
    f16* Wht   = (f16*)(ws + (10u << 20));                // 1 MB
    f16* Wrt   = (f16*)(ws + (11u << 20));                // 1 MB
    f16* xh2   = (f16*)(ws + (12u << 20));                // 4 MB  [32][4096][16] swizzled
    float* a2    = (float*)(ws + (16u << 20));            // 128 KB
    float* b2    = a2 + 8 * 4096;
    float* ABpre = b2 + 8 * 4096;
    float* Bpre  = ABpre + 2 * 8 * 4096;
    unsigned int* M2e = (unsigned int*)(Bpre + 2 * 8 * 4096);

    hipLaunchKernelGGL(k_mask, dim3(1024), dim3(256), 0, stream, graph, maskT, M2e);
    hipLaunchKernelGGL(k_pre, dim3(1536), dim3(256), 0, stream, x, xh2, W, Wht, Wr, Wrt);
    hipLaunchKernelGGL(k_gemm_h, dim3(512), dim3(256), 0, stream, xh2, Wht, hbT2);
    hipLaunchKernelGGL(k_ab, dim3(128), dim3(256), 0, stream, hbT2, wi, wj, a2, b2, M2e);
    hipLaunchKernelGGL(k_prep, dim3(128), dim3(256), 0, stream, a2, b2, M2e, ABpre, Bpre);
    hipLaunchKernelGGL(k_main, dim3(1024), dim3(256), 0, stream, xh2, hbT2, Wrt, maskT,
                       ABpre, Bpre, bias, out);
}